// Round 1
// baseline (879.762 us; speedup 1.0000x reference)
//
#include <hip/hip_runtime.h>
#include <hip/hip_bf16.h>
#include <float.h>

// Problem constants
#define B_  2
#define S_  2048
#define N_  1024
#define H_  1024
#define NH_ 16
#define D_  64

// ---------------------------------------------------------------------------
// GEMM: Y[M,Nc] = X[M,K] @ W[Nc,K]^T   (nn.Linear, no bias)
// 64x64 tile per 256-thread block, BK=16, 4x4 outputs per thread, fp32.
// ---------------------------------------------------------------------------
__global__ __launch_bounds__(256) void gemm_xwT(const float* __restrict__ X,
                                                const float* __restrict__ W,
                                                float* __restrict__ Y,
                                                int M, int Nc, int K) {
    __shared__ __align__(16) float As[16][68];  // As[k][m], pad 68 for b128-aligned conflict-free reads
    __shared__ __align__(16) float Bs[16][68];  // Bs[k][n]
    const int bm = blockIdx.y * 64;
    const int bn = blockIdx.x * 64;
    const int tid = threadIdx.x;
    const int tx = tid & 15;       // 0..15  -> n
    const int ty = tid >> 4;       // 0..15  -> m
    const int lm = tid >> 2;       // 0..63  row of tile to load
    const int lk = (tid & 3) << 2; // 0,4,8,12 col offset (float4)

    float acc[4][4] = {};

    for (int k0 = 0; k0 < K; k0 += 16) {
        float4 a = *(const float4*)(X + (size_t)(bm + lm) * K + k0 + lk);
        float4 b = *(const float4*)(W + (size_t)(bn + lm) * K + k0 + lk);
        As[lk + 0][lm] = a.x; As[lk + 1][lm] = a.y; As[lk + 2][lm] = a.z; As[lk + 3][lm] = a.w;
        Bs[lk + 0][lm] = b.x; Bs[lk + 1][lm] = b.y; Bs[lk + 2][lm] = b.z; Bs[lk + 3][lm] = b.w;
        __syncthreads();
#pragma unroll
        for (int kk = 0; kk < 16; ++kk) {
            float4 av = *(const float4*)&As[kk][ty * 4];
            float4 bv = *(const float4*)&Bs[kk][tx * 4];
            float a0[4] = {av.x, av.y, av.z, av.w};
            float b0[4] = {bv.x, bv.y, bv.z, bv.w};
#pragma unroll
            for (int i = 0; i < 4; ++i)
#pragma unroll
                for (int j = 0; j < 4; ++j)
                    acc[i][j] = fmaf(a0[i], b0[j], acc[i][j]);
        }
        __syncthreads();
    }
#pragma unroll
    for (int i = 0; i < 4; ++i) {
        float4 o = make_float4(acc[i][0], acc[i][1], acc[i][2], acc[i][3]);
        *(float4*)(Y + (size_t)(bm + ty * 4 + i) * Nc + bn + tx * 4) = o;
    }
}

// ---------------------------------------------------------------------------
// cnt[t] = number of block_ends <= t  (block_ends sorted ascending)
// ---------------------------------------------------------------------------
__global__ void count_kernel(const int* __restrict__ ends, int* __restrict__ cnt) {
    int t = blockIdx.x * 256 + threadIdx.x;
    if (t >= S_) return;
    int lo = 0, hi = N_;
    while (lo < hi) {
        int mid = (lo + hi) >> 1;
        if (ends[mid] <= t) lo = mid + 1; else hi = mid;
    }
    cnt[t] = lo;
}

// ---------------------------------------------------------------------------
// Flash-style attention. One WG (256 thr) = one (b, h) and 32 query rows.
// 8 lanes per query row. KV iterated in 64-block tiles through LDS.
// Masked score = -FLT_MAX (matches reference's finfo.min semantics exactly,
// including the uniform-softmax behavior of fully-masked rows).
// ---------------------------------------------------------------------------
__global__ __launch_bounds__(256) void attn_kernel(const float* __restrict__ Qp,
                                                   const float* __restrict__ Kp,
                                                   const float* __restrict__ Vp,
                                                   const int* __restrict__ cnt,
                                                   float* __restrict__ AO) {
    __shared__ __align__(16) float qs[32][68];
    __shared__ __align__(16) float ks[64][68];
    __shared__ __align__(16) float vs[64][68];
    __shared__ float ps[32][65];

    const int b = blockIdx.z;
    const int h = blockIdx.y;
    const int t0 = blockIdx.x * 32;
    const int tid = threadIdx.x;
    const int r = tid >> 3;   // query row 0..31
    const int g = tid & 7;    // lane group 0..7

    // Load Q tile: 32 rows x 64 cols (this WG's head slice)
    for (int i = tid; i < 32 * 16; i += 256) {
        int rr = i >> 4;
        int cc = (i & 15) << 2;
        *(float4*)&qs[rr][cc] =
            *(const float4*)(Qp + ((size_t)(b * S_ + t0 + rr)) * H_ + h * 64 + cc);
    }
    const int cnt_r = cnt[t0 + r];

    float m_run = -FLT_MAX;
    float l_run = 0.0f;
    float o[8] = {};

    __syncthreads();

    for (int nt = 0; nt < N_ / 64; ++nt) {
        // Stage K and V tiles (64 blocks x 64 dims)
        for (int i = tid; i < 64 * 16; i += 256) {
            int rr = i >> 4;
            int cc = (i & 15) << 2;
            size_t row = (size_t)(b * N_ + nt * 64 + rr) * H_ + h * 64 + cc;
            *(float4*)&ks[rr][cc] = *(const float4*)(Kp + row);
            *(float4*)&vs[rr][cc] = *(const float4*)(Vp + row);
        }
        __syncthreads();

        // Scores: thread (r,g) computes n_local = j*8+g  (g-inner => conflict-free ks reads)
        float sc[8];
        float mx = -FLT_MAX;
#pragma unroll
        for (int j = 0; j < 8; ++j) {
            int nl = j * 8 + g;
            float s = 0.f;
#pragma unroll
            for (int d4 = 0; d4 < 16; ++d4) {
                float4 qv = *(const float4*)&qs[r][d4 * 4];
                float4 kv = *(const float4*)&ks[nl][d4 * 4];
                s = fmaf(qv.x, kv.x, s);
                s = fmaf(qv.y, kv.y, s);
                s = fmaf(qv.z, kv.z, s);
                s = fmaf(qv.w, kv.w, s);
            }
            s *= 0.125f;  // 1/sqrt(64)
            int n = nt * 64 + nl;
            if (n >= cnt_r) s = -FLT_MAX;  // reference masks with finfo.min
            sc[j] = s;
            mx = fmaxf(mx, s);
        }
        // row-max over the 8 lanes of this row
        mx = fmaxf(mx, __shfl_xor(mx, 1));
        mx = fmaxf(mx, __shfl_xor(mx, 2));
        mx = fmaxf(mx, __shfl_xor(mx, 4));
        float new_m = fmaxf(m_run, mx);
        float alpha = __expf(m_run - new_m);  // 0-0 = 0 -> 1 for still-all-masked rows

        float lsum = 0.f;
#pragma unroll
        for (int j = 0; j < 8; ++j) {
            float p = __expf(sc[j] - new_m);
            ps[r][j * 8 + g] = p;
            lsum += p;
        }
        lsum += __shfl_xor(lsum, 1);
        lsum += __shfl_xor(lsum, 2);
        lsum += __shfl_xor(lsum, 4);
        l_run = l_run * alpha + lsum;
        m_run = new_m;
        __syncthreads();

        // O update: thread (r,g) owns cols d = g*8 .. g*8+7
#pragma unroll
        for (int j = 0; j < 8; ++j) o[j] *= alpha;
#pragma unroll 8
        for (int n = 0; n < 64; ++n) {
            float p = ps[r][n];
            float4 v0 = *(const float4*)&vs[n][g * 8];
            float4 v1 = *(const float4*)&vs[n][g * 8 + 4];
            o[0] = fmaf(p, v0.x, o[0]);
            o[1] = fmaf(p, v0.y, o[1]);
            o[2] = fmaf(p, v0.z, o[2]);
            o[3] = fmaf(p, v0.w, o[3]);
            o[4] = fmaf(p, v1.x, o[4]);
            o[5] = fmaf(p, v1.y, o[5]);
            o[6] = fmaf(p, v1.z, o[6]);
            o[7] = fmaf(p, v1.w, o[7]);
        }
        __syncthreads();
    }

    float inv_l = 1.0f / l_run;  // l >= 1 always (fully-masked rows have l = N)
    float* op = AO + ((size_t)(b * S_ + t0 + r)) * H_ + h * 64 + g * 8;
    float4 w0 = make_float4(o[0] * inv_l, o[1] * inv_l, o[2] * inv_l, o[3] * inv_l);
    float4 w1 = make_float4(o[4] * inv_l, o[5] * inv_l, o[6] * inv_l, o[7] * inv_l);
    *(float4*)(op + 0) = w0;
    *(float4*)(op + 4) = w1;
}

// ---------------------------------------------------------------------------
extern "C" void kernel_launch(void* const* d_in, const int* in_sizes, int n_in,
                              void* d_out, int out_size, void* d_ws, size_t ws_size,
                              hipStream_t stream) {
    const float* token_q   = (const float*)d_in[0];
    const float* block_kv  = (const float*)d_in[1];
    const int*   block_ends = (const int*)d_in[2];
    const float* Wq = (const float*)d_in[3];
    const float* Wk = (const float*)d_in[4];
    const float* Wv = (const float*)d_in[5];
    const float* Wo = (const float*)d_in[6];
    float* out = (float*)d_out;

    // Workspace layout (floats):
    //   Kp: [B*N, H] = 2M    Vp: 2M    Qp: [B*S, H] = 4M (AO aliases Qp — each
    //   Qp element is read only by the unique WG that later overwrites it, and
    //   the read completes before the WG's first __syncthreads barrier drain).
    float* ws = (float*)d_ws;
    float* Kp = ws;
    float* Vp = ws + (size_t)B_ * N_ * H_;
    float* Qp = ws + (size_t)2 * B_ * N_ * H_;
    int*   cnt = (int*)(ws + (size_t)2 * B_ * N_ * H_ + (size_t)B_ * S_ * H_);

    dim3 blk(256);

    // Projections
    gemm_xwT<<<dim3(H_ / 64, (B_ * S_) / 64), blk, 0, stream>>>(token_q, Wq, Qp, B_ * S_, H_, H_);
    gemm_xwT<<<dim3(H_ / 64, (B_ * N_) / 64), blk, 0, stream>>>(block_kv, Wk, Kp, B_ * N_, H_, H_);
    gemm_xwT<<<dim3(H_ / 64, (B_ * N_) / 64), blk, 0, stream>>>(block_kv, Wv, Vp, B_ * N_, H_, H_);

    // Visibility prefix counts
    count_kernel<<<dim3(S_ / 256), blk, 0, stream>>>(block_ends, cnt);

    // Attention (AO written in-place over Qp)
    attn_kernel<<<dim3(S_ / 32, NH_, B_), blk, 0, stream>>>(Qp, Kp, Vp, cnt, Qp);

    // Output projection
    gemm_xwT<<<dim3(H_ / 64, (B_ * S_) / 64), blk, 0, stream>>>(Qp, Wo, out, B_ * S_, H_, H_);
}

// Round 2
// 204.931 us; speedup vs baseline: 4.2930x; 4.2930x over previous
//
#include <hip/hip_runtime.h>
#include <float.h>
#include <stdint.h>

#define B_  2
#define S_  2048
#define N_  1024
#define H_  1024
#define NH_ 16
#define K_  1024

typedef __attribute__((ext_vector_type(8))) short bf16x8;
typedef __attribute__((ext_vector_type(4))) float f32x4;

typedef __attribute__((address_space(3))) uint32_t lds_u32;
typedef __attribute__((address_space(1))) uint32_t glb_u32;

// async global->LDS, 16B per lane; LDS dest = wave-uniform base + lane*16
__device__ __forceinline__ void gload16(void* l, const void* g) {
    __builtin_amdgcn_global_load_lds((const glb_u32*)g, (lds_u32*)l, 16, 0, 0);
}

// round-to-nearest-even fp32 -> bf16 bits
__device__ __forceinline__ ushort f2bf(float f) {
    uint32_t u = __float_as_uint(f);
    u = (u + 0x7fffu + ((u >> 16) & 1u)) >> 16;
    return (ushort)u;
}

// ---------------------------------------------------------------------------
// fp32 -> bf16 elementwise (8 elems/thread)
// ---------------------------------------------------------------------------
__global__ __launch_bounds__(256) void cvt_f2b(const float* __restrict__ x, ushort* __restrict__ y) {
    int i = (blockIdx.x * 256 + threadIdx.x) * 8;
    float4 a = *(const float4*)(x + i);
    float4 b = *(const float4*)(x + i + 4);
    ushort4 o0; o0.x = f2bf(a.x); o0.y = f2bf(a.y); o0.z = f2bf(a.z); o0.w = f2bf(a.w);
    ushort4 o1; o1.x = f2bf(b.x); o1.y = f2bf(b.y); o1.z = f2bf(b.z); o1.w = f2bf(b.w);
    *(ushort4*)(y + i) = o0;
    *(ushort4*)(y + i + 4) = o1;
}

// ---------------------------------------------------------------------------
// cnt[t] = #(block_ends <= t); block visible iff n < cnt[t]
// ---------------------------------------------------------------------------
__global__ void count_kernel(const int* __restrict__ ends, int* __restrict__ cnt) {
    int t = blockIdx.x * 256 + threadIdx.x;
    if (t >= S_) return;
    int lo = 0, hi = N_;
    while (lo < hi) {
        int mid = (lo + hi) >> 1;
        if (ends[mid] <= t) lo = mid + 1; else hi = mid;
    }
    cnt[t] = lo;
}

// ---------------------------------------------------------------------------
// 128x128-tile bf16 MFMA GEMM: Y = X[M,K] @ W[1024,K]^T.  512 thr = 8 waves
// (4x2 wave grid, 32x64 C each). BK=64. XOR-swizzled LDS (seg ^ row&7) staged
// via global_load_lds width=16.  Epilogue kinds: 0 = bf16 row-major,
// 1 = fp32 row-major, 2 = V-transposed per head (Vt[(b*16+h)*64+d][n_kv]).
// gridDim.z==2 => KV mode: z=0 -> Wa/Ya kind0 (K), z=1 -> Wb/Yb kind2 (Vt).
// ---------------------------------------------------------------------------
__global__ __launch_bounds__(512) void gemm128(const ushort* __restrict__ X,
                                               const ushort* __restrict__ Wa,
                                               const ushort* __restrict__ Wb,
                                               void* Ya, void* Yb, int kind0)
{
    __shared__ __align__(16) ushort smem[17408];   // Xs[0..8191] Ws[8192..16383]; reuse for Vt transpose
    ushort* Xs = smem;
    ushort* Ws = smem + 8192;

    const ushort* W; void* Yp; int kind;
    if (gridDim.z == 2) {
        if (blockIdx.z == 0) { W = Wa; Yp = Ya; kind = 0; }
        else                 { W = Wb; Yp = Yb; kind = 2; }
    } else { W = Wa; Yp = Ya; kind = kind0; }

    const int bm = blockIdx.y * 128;
    const int bn = blockIdx.x * 128;
    const int tid = threadIdx.x;
    const int lane = tid & 63, w = tid >> 6;   // 8 waves
    const int wy = w >> 1, wx = w & 1;         // wave: 32 (m) x 64 (n)
    const int c = lane & 15, g = lane >> 4;

    f32x4 acc[2][4] = {};

    for (int kt = 0; kt < 16; ++kt) {
        const int k0 = kt * 64;
        // stage Xs and Ws: 1024 16B-units each; wave w covers units [w*128, w*128+128)
#pragma unroll
        for (int j = 0; j < 2; ++j) {
            int u = w * 128 + j * 64 + lane;
            int row = u >> 3, gs = (u & 7) ^ (row & 7);
            gload16(Xs + (w * 128 + j * 64) * 8, X + (size_t)(bm + row) * K_ + k0 + gs * 8);
            gload16(Ws + (w * 128 + j * 64) * 8, W + (size_t)(bn + row) * K_ + k0 + gs * 8);
        }
        __syncthreads();
#pragma unroll
        for (int ks = 0; ks < 2; ++ks) {
            bf16x8 af[2], bfr[4];
#pragma unroll
            for (int mi = 0; mi < 2; ++mi) {
                int row = wy * 32 + mi * 16 + c;
                int s = ks * 4 + g;
                af[mi] = *(const bf16x8*)(Xs + (row * 8 + (s ^ (row & 7))) * 8);
            }
#pragma unroll
            for (int ni = 0; ni < 4; ++ni) {
                int row = wx * 64 + ni * 16 + c;
                int s = ks * 4 + g;
                bfr[ni] = *(const bf16x8*)(Ws + (row * 8 + (s ^ (row & 7))) * 8);
            }
#pragma unroll
            for (int mi = 0; mi < 2; ++mi)
#pragma unroll
                for (int ni = 0; ni < 4; ++ni)
                    acc[mi][ni] = __builtin_amdgcn_mfma_f32_16x16x32_bf16(af[mi], bfr[ni], acc[mi][ni], 0, 0, 0);
        }
        __syncthreads();
    }

    if (kind == 0) {
        ushort* Y = (ushort*)Yp;
#pragma unroll
        for (int mi = 0; mi < 2; ++mi)
#pragma unroll
            for (int ni = 0; ni < 4; ++ni)
#pragma unroll
                for (int r = 0; r < 4; ++r) {
                    int row = bm + wy * 32 + mi * 16 + g * 4 + r;
                    int col = bn + wx * 64 + ni * 16 + c;
                    Y[(size_t)row * 1024 + col] = f2bf(acc[mi][ni][r]);
                }
    } else if (kind == 1) {
        float* Y = (float*)Yp;
#pragma unroll
        for (int mi = 0; mi < 2; ++mi)
#pragma unroll
            for (int ni = 0; ni < 4; ++ni)
#pragma unroll
                for (int r = 0; r < 4; ++r) {
                    int row = bm + wy * 32 + mi * 16 + g * 4 + r;
                    int col = bn + wx * 64 + ni * 16 + c;
                    Y[(size_t)row * 1024 + col] = acc[mi][ni][r];
                }
    } else {
        // V transposed: T[n_c_local][m_local] then coalesced rows to Vt global
        ushort* T = smem;                       // [128][136]
#pragma unroll
        for (int mi = 0; mi < 2; ++mi)
#pragma unroll
            for (int ni = 0; ni < 4; ++ni) {
                ushort4 v4;
                v4.x = f2bf(acc[mi][ni][0]); v4.y = f2bf(acc[mi][ni][1]);
                v4.z = f2bf(acc[mi][ni][2]); v4.w = f2bf(acc[mi][ni][3]);
                *(ushort4*)&T[(wx * 64 + ni * 16 + c) * 136 + wy * 32 + mi * 16 + g * 4] = v4;
            }
        __syncthreads();
        ushort* Vt = (ushort*)Yp;
        int b = bm >> 10;                       // M = B*N_
        int rid = tid >> 2, quad = tid & 3;     // 128 rows x 4 x 64B
        int n_c = bn + rid;
        int h = n_c >> 6, d = n_c & 63;
        int m0 = quad * 32;
        ushort* dst = Vt + (size_t)((b * NH_ + h) * 64 + d) * N_ + (bm & (N_ - 1)) + m0;
#pragma unroll
        for (int jj = 0; jj < 4; ++jj)
            *(uint4*)(dst + jj * 8) = *(const uint4*)&T[rid * 136 + m0 + jj * 8];
    }
}

// ---------------------------------------------------------------------------
// Flash-MFMA attention. WG = 256 thr (4 waves) = one (b,h) x 64 queries.
// Wave w owns 16 queries. Per 64-KV tile: S^T = K·Q^T (A=K rows, B=Q rows),
// softmax in S^T C-layout (query = lane&15), P -> Ps[m][n] as ushort4,
// O = P·V (A=Ps rows, B=Vt rows). Masked score = -FLT_MAX (= finfo.min).
// ---------------------------------------------------------------------------
__global__ __launch_bounds__(256) void attn_mfma(const ushort* __restrict__ Qp,
                                                 const ushort* __restrict__ Kp,
                                                 const ushort* __restrict__ VtG,
                                                 const int* __restrict__ cnt,
                                                 ushort* __restrict__ AO)
{
    __shared__ __align__(16) ushort Qs[64 * 64];
    __shared__ __align__(16) ushort Ks[64 * 64];
    __shared__ __align__(16) ushort Vs[64 * 64];
    __shared__ __align__(16) ushort Ps[64][72];

    const int b = blockIdx.z, h = blockIdx.y, t0 = blockIdx.x * 64;
    const int tid = threadIdx.x, lane = tid & 63, w = tid >> 6;
    const int c = lane & 15, g = lane >> 4;

    // stage Q tile (64 q x 64 d), swizzled
#pragma unroll
    for (int j = 0; j < 2; ++j) {
        int u = (w * 2 + j) * 64 + lane;
        int row = u >> 3, gs = (u & 7) ^ (row & 7);
        gload16(Qs + (w * 2 + j) * 512, Qp + (size_t)(b * S_ + t0 + row) * H_ + h * 64 + gs * 8);
    }
    const int cntv = cnt[t0 + w * 16 + c];   // this lane's query = t0 + w*16 + c

    float m_run = -FLT_MAX, l_run = 0.f;
    f32x4 o[4] = {};

    for (int nt = 0; nt < 16; ++nt) {
        // stage K tile (rows = kv n) and Vt tile (rows = d), swizzled
#pragma unroll
        for (int j = 0; j < 2; ++j) {
            int u = (w * 2 + j) * 64 + lane;
            int row = u >> 3, gs = (u & 7) ^ (row & 7);
            gload16(Ks + (w * 2 + j) * 512, Kp + (size_t)(b * N_ + nt * 64 + row) * H_ + h * 64 + gs * 8);
            gload16(Vs + (w * 2 + j) * 512, VtG + (size_t)((b * NH_ + h) * 64 + row) * N_ + nt * 64 + gs * 8);
        }
        __syncthreads();

        // S^T = K · Q^T  (4 ntiles x 2 ksubs)
        bf16x8 bq[2];
#pragma unroll
        for (int ks = 0; ks < 2; ++ks) {
            int row = w * 16 + c;
            int s = ks * 4 + g;
            bq[ks] = *(const bf16x8*)(Qs + (row * 8 + (s ^ (row & 7))) * 8);
        }
        f32x4 st[4] = {};
#pragma unroll
        for (int ntile = 0; ntile < 4; ++ntile)
#pragma unroll
            for (int ks = 0; ks < 2; ++ks) {
                int row = ntile * 16 + c;
                int s = ks * 4 + g;
                bf16x8 ak = *(const bf16x8*)(Ks + (row * 8 + (s ^ (row & 7))) * 8);
                st[ntile] = __builtin_amdgcn_mfma_f32_16x16x32_bf16(ak, bq[ks], st[ntile], 0, 0, 0);
            }

        // mask + online softmax; per-query stats live in lanes sharing lane&15
        float sc[4][4];
        float mloc = -FLT_MAX;
#pragma unroll
        for (int ntile = 0; ntile < 4; ++ntile)
#pragma unroll
            for (int r = 0; r < 4; ++r) {
                int n_glob = nt * 64 + ntile * 16 + g * 4 + r;
                float v = st[ntile][r] * 0.125f;
                if (n_glob >= cntv) v = -FLT_MAX;
                sc[ntile][r] = v;
                mloc = fmaxf(mloc, v);
            }
        mloc = fmaxf(mloc, __shfl_xor(mloc, 16));
        mloc = fmaxf(mloc, __shfl_xor(mloc, 32));
        float m_new = fmaxf(m_run, mloc);
        float alpha = __expf(m_run - m_new);   // -FLT_MAX - -FLT_MAX = 0 -> 1
        float lsum = 0.f;
#pragma unroll
        for (int ntile = 0; ntile < 4; ++ntile) {
            float p0 = __expf(sc[ntile][0] - m_new);
            float p1 = __expf(sc[ntile][1] - m_new);
            float p2 = __expf(sc[ntile][2] - m_new);
            float p3 = __expf(sc[ntile][3] - m_new);
            lsum += p0 + p1 + p2 + p3;
            ushort4 p4; p4.x = f2bf(p0); p4.y = f2bf(p1); p4.z = f2bf(p2); p4.w = f2bf(p3);
            *(ushort4*)&Ps[w * 16 + c][ntile * 16 + g * 4] = p4;   // wave-private rows
        }
        lsum += __shfl_xor(lsum, 16);
        lsum += __shfl_xor(lsum, 32);
        l_run = l_run * alpha + lsum;
        m_run = m_new;

        // O rescale (alpha per O-row = query g*4+r, broadcast from lanes 0..15)
        float ar[4];
#pragma unroll
        for (int r = 0; r < 4; ++r) ar[r] = __shfl(alpha, g * 4 + r);

        bf16x8 ap[2];
#pragma unroll
        for (int ks = 0; ks < 2; ++ks)
            ap[ks] = *(const bf16x8*)&Ps[w * 16 + c][ks * 32 + g * 8];
#pragma unroll
        for (int dt = 0; dt < 4; ++dt) {
            f32x4 oo = o[dt];
#pragma unroll
            for (int r = 0; r < 4; ++r) oo[r] *= ar[r];
#pragma unroll
            for (int ks = 0; ks < 2; ++ks) {
                int row = dt * 16 + c;
                int s = ks * 4 + g;
                bf16x8 bv = *(const bf16x8*)(Vs + (row * 8 + (s ^ (row & 7))) * 8);
                oo = __builtin_amdgcn_mfma_f32_16x16x32_bf16(ap[ks], bv, oo, 0, 0, 0);
            }
            o[dt] = oo;
        }
        __syncthreads();
    }

    float lr[4];
    float invl = 1.f / l_run;
#pragma unroll
    for (int r = 0; r < 4; ++r) lr[r] = __shfl(invl, g * 4 + r);
#pragma unroll
    for (int dt = 0; dt < 4; ++dt)
#pragma unroll
        for (int r = 0; r < 4; ++r) {
            int q = t0 + w * 16 + g * 4 + r;
            AO[(size_t)(b * S_ + q) * H_ + h * 64 + dt * 16 + c] = f2bf(o[dt][r] * lr[r]);
        }
}

// ---------------------------------------------------------------------------
extern "C" void kernel_launch(void* const* d_in, const int* in_sizes, int n_in,
                              void* d_out, int out_size, void* d_ws, size_t ws_size,
                              hipStream_t stream) {
    const float* token_q    = (const float*)d_in[0];
    const float* block_kv   = (const float*)d_in[1];
    const int*   block_ends = (const int*)d_in[2];
    const float* Wq = (const float*)d_in[3];
    const float* Wk = (const float*)d_in[4];
    const float* Wv = (const float*)d_in[5];
    const float* Wo = (const float*)d_in[6];
    float* out = (float*)d_out;

    // Workspace (ushort units). Region A (4M ushorts = 8MB): first qx (bf16
    // token_q, consumed by Q-proj), then reused as Kp (2M) + VtG (2M) by the
    // KV-proj launch (strictly after Q-proj on the stream). AO aliases Qp
    // (per-WG read-before-write in attn).
    ushort* ws  = (ushort*)d_ws;
    ushort* qx  = ws;                                   // 4M  (-> reused: Kp, VtG)
    ushort* Kp  = ws;                                   // 2M
    ushort* VtG = ws + (size_t)2 * 1024 * 1024;         // 2M
    ushort* kvx = ws + (size_t)4 * 1024 * 1024;         // 2M
    ushort* wqb = ws + (size_t)6 * 1024 * 1024;         // 1M
    ushort* wkb = ws + (size_t)7 * 1024 * 1024;         // 1M
    ushort* wvb = ws + (size_t)8 * 1024 * 1024;         // 1M
    ushort* wob = ws + (size_t)9 * 1024 * 1024;         // 1M
    ushort* Qp  = ws + (size_t)10 * 1024 * 1024;        // 4M (AO aliases)
    int*    cnt = (int*)(ws + (size_t)14 * 1024 * 1024);

    // converts
    cvt_f2b<<<2048, 256, 0, stream>>>(token_q, qx);
    cvt_f2b<<<1024, 256, 0, stream>>>(block_kv, kvx);
    cvt_f2b<<<512, 256, 0, stream>>>(Wq, wqb);
    cvt_f2b<<<512, 256, 0, stream>>>(Wk, wkb);
    cvt_f2b<<<512, 256, 0, stream>>>(Wv, wvb);
    cvt_f2b<<<512, 256, 0, stream>>>(Wo, wob);
    count_kernel<<<8, 256, 0, stream>>>(block_ends, cnt);

    // Q projection: [4096,1024] -> Qp bf16
    gemm128<<<dim3(8, 32, 1), 512, 0, stream>>>(qx, wqb, wqb, Qp, Qp, 0);
    // K + V projections: [2048,1024] -> Kp bf16 rowmajor, VtG transposed
    gemm128<<<dim3(8, 16, 2), 512, 0, stream>>>(kvx, wkb, wvb, Kp, VtG, 0);
    // attention -> AO (aliases Qp)
    attn_mfma<<<dim3(32, 16, 2), 256, 0, stream>>>(Qp, Kp, VtG, cnt, Qp);
    // output projection: AO @ Wo^T -> fp32 out
    gemm128<<<dim3(8, 32, 1), 512, 0, stream>>>(Qp, wob, wob, out, out, 1);
}

// Round 3
// 186.826 us; speedup vs baseline: 4.7090x; 1.0969x over previous
//
#include <hip/hip_runtime.h>
#include <float.h>
#include <stdint.h>

#define B_  2
#define S_  2048
#define N_  1024
#define H_  1024
#define NH_ 16
#define K_  1024

typedef __attribute__((ext_vector_type(8))) short bf16x8;
typedef __attribute__((ext_vector_type(4))) float f32x4;

typedef __attribute__((address_space(3))) uint32_t lds_u32;
typedef __attribute__((address_space(1))) uint32_t glb_u32;

// async global->LDS, 16B per lane; LDS dest = wave-uniform base + lane*16
__device__ __forceinline__ void gload16(void* l, const void* g) {
    __builtin_amdgcn_global_load_lds((const glb_u32*)g, (lds_u32*)l, 16, 0, 0);
}

// round-to-nearest-even fp32 -> bf16 bits
__device__ __forceinline__ ushort f2bf(float f) {
    uint32_t u = __float_as_uint(f);
    u = (u + 0x7fffu + ((u >> 16) & 1u)) >> 16;
    return (ushort)u;
}

// pack two fp32 -> two bf16 in one uint (low = a)
#if __has_builtin(__builtin_amdgcn_cvt_pk_bf16_f32)
typedef __attribute__((ext_vector_type(2))) __bf16 bfp2;
__device__ __forceinline__ uint pk2(float a, float b) {
    bfp2 v = __builtin_amdgcn_cvt_pk_bf16_f32(a, b);
    return __builtin_bit_cast(uint, v);
}
#else
__device__ __forceinline__ uint pk2(float a, float b) {
    return (uint)f2bf(a) | ((uint)f2bf(b) << 16);
}
#endif

__device__ __forceinline__ float fexp2(float x) {
#if __has_builtin(__builtin_amdgcn_exp2f)
    return __builtin_amdgcn_exp2f(x);
#else
    return __expf(x * 0.69314718f);
#endif
}

// ---------------------------------------------------------------------------
// Fused prep: all fp32->bf16 converts (7 regions laid out contiguously in ws)
// + visibility prefix counts. 2048 elems per block.
// ---------------------------------------------------------------------------
__global__ __launch_bounds__(256) void prep_kernel(const float* __restrict__ tq,
        const float* __restrict__ kv, const float* __restrict__ wq,
        const float* __restrict__ wk, const float* __restrict__ wv,
        const float* __restrict__ wo, const int* __restrict__ ends,
        ushort* __restrict__ dst, int* __restrict__ cnt)
{
    int blk = blockIdx.x;
    if (blk >= 5120) {
        int t = (blk - 5120) * 256 + threadIdx.x;
        if (t < S_) {
            int lo = 0, hi = N_;
            while (lo < hi) { int mid = (lo + hi) >> 1; if (ends[mid] <= t) lo = mid + 1; else hi = mid; }
            cnt[t] = lo;
        }
        return;
    }
    const float* src; size_t base;
    if (blk < 2048)      { src = tq; base = 0;       }
    else if (blk < 3072) { src = kv; base = 4194304; blk -= 2048; }
    else if (blk < 3584) { src = wq; base = 6291456; blk -= 3072; }
    else if (blk < 4096) { src = wk; base = 7340032; blk -= 3584; }
    else if (blk < 4608) { src = wv; base = 8388608; blk -= 4096; }
    else                 { src = wo; base = 9437184; blk -= 4608; }
    size_t i = (size_t)blk * 2048 + threadIdx.x * 8;
    float4 a = *(const float4*)(src + i);
    float4 b = *(const float4*)(src + i + 4);
    uint4 o;
    o.x = pk2(a.x, a.y); o.y = pk2(a.z, a.w);
    o.z = pk2(b.x, b.y); o.w = pk2(b.z, b.w);
    *(uint4*)(dst + base + i) = o;
}

// ---------------------------------------------------------------------------
// Vmean[row] = mean over n of Vt[row][n]; row = (b*16+h)*64 + d. One wave/row.
// (This is the reference's uniform-softmax output for fully-masked queries.)
// ---------------------------------------------------------------------------
__global__ __launch_bounds__(256) void vmean_kernel(const ushort* __restrict__ Vt,
                                                    float* __restrict__ Vm)
{
    int row = blockIdx.x * 4 + (threadIdx.x >> 6);
    int lane = threadIdx.x & 63;
    const ushort* p = Vt + (size_t)row * N_ + lane * 16;
    uint4 a = *(const uint4*)p;
    uint4 b = *(const uint4*)(p + 8);
    uint u[8] = {a.x, a.y, a.z, a.w, b.x, b.y, b.z, b.w};
    float s = 0.f;
#pragma unroll
    for (int j = 0; j < 8; ++j) {
        s += __uint_as_float(u[j] << 16);
        s += __uint_as_float(u[j] & 0xffff0000u);
    }
#pragma unroll
    for (int off = 1; off < 64; off <<= 1) s += __shfl_xor(s, off);
    if (lane == 0) Vm[row] = s * (1.f / 1024.f);
}

// ---------------------------------------------------------------------------
// 128x128-tile bf16 MFMA GEMM: Y = X[M,K] @ W[1024,K]^T.  512 thr = 8 waves
// (4x2 wave grid, 32x64 C each). BK=64. XOR-swizzled LDS staged via
// global_load_lds width=16. kinds: 0 = bf16 rowmajor, 1 = fp32 rowmajor,
// 2 = V-transposed per head (Vt[(b*16+h)*64+d][n]).
// gridDim.z==2 => KV mode: z=0 -> Wa/Ya kind0 (K), z=1 -> Wb/Yb kind2 (Vt).
// ---------------------------------------------------------------------------
__global__ __launch_bounds__(512) void gemm128(const ushort* __restrict__ X,
                                               const ushort* __restrict__ Wa,
                                               const ushort* __restrict__ Wb,
                                               void* Ya, void* Yb, int kind0)
{
    __shared__ __align__(16) ushort smem[17408];
    ushort* Xs = smem;
    ushort* Ws = smem + 8192;

    const ushort* W; void* Yp; int kind;
    if (gridDim.z == 2) {
        if (blockIdx.z == 0) { W = Wa; Yp = Ya; kind = 0; }
        else                 { W = Wb; Yp = Yb; kind = 2; }
    } else { W = Wa; Yp = Ya; kind = kind0; }

    const int bm = blockIdx.y * 128;
    const int bn = blockIdx.x * 128;
    const int tid = threadIdx.x;
    const int lane = tid & 63, w = tid >> 6;
    const int wy = w >> 1, wx = w & 1;
    const int c = lane & 15, g = lane >> 4;

    f32x4 acc[2][4] = {};

    for (int kt = 0; kt < 16; ++kt) {
        const int k0 = kt * 64;
#pragma unroll
        for (int j = 0; j < 2; ++j) {
            int u = w * 128 + j * 64 + lane;
            int row = u >> 3, gs = (u & 7) ^ (row & 7);
            gload16(Xs + (w * 128 + j * 64) * 8, X + (size_t)(bm + row) * K_ + k0 + gs * 8);
            gload16(Ws + (w * 128 + j * 64) * 8, W + (size_t)(bn + row) * K_ + k0 + gs * 8);
        }
        __syncthreads();
#pragma unroll
        for (int ks = 0; ks < 2; ++ks) {
            bf16x8 af[2], bfr[4];
#pragma unroll
            for (int mi = 0; mi < 2; ++mi) {
                int row = wy * 32 + mi * 16 + c;
                int s = ks * 4 + g;
                af[mi] = *(const bf16x8*)(Xs + (row * 8 + (s ^ (row & 7))) * 8);
            }
#pragma unroll
            for (int ni = 0; ni < 4; ++ni) {
                int row = wx * 64 + ni * 16 + c;
                int s = ks * 4 + g;
                bfr[ni] = *(const bf16x8*)(Ws + (row * 8 + (s ^ (row & 7))) * 8);
            }
#pragma unroll
            for (int mi = 0; mi < 2; ++mi)
#pragma unroll
                for (int ni = 0; ni < 4; ++ni)
                    acc[mi][ni] = __builtin_amdgcn_mfma_f32_16x16x32_bf16(af[mi], bfr[ni], acc[mi][ni], 0, 0, 0);
        }
        __syncthreads();
    }

    if (kind == 0) {
        ushort* Y = (ushort*)Yp;
#pragma unroll
        for (int mi = 0; mi < 2; ++mi)
#pragma unroll
            for (int ni = 0; ni < 4; ++ni)
#pragma unroll
                for (int r = 0; r < 4; ++r) {
                    int row = bm + wy * 32 + mi * 16 + g * 4 + r;
                    int col = bn + wx * 64 + ni * 16 + c;
                    Y[(size_t)row * 1024 + col] = f2bf(acc[mi][ni][r]);
                }
    } else if (kind == 1) {
        float* Y = (float*)Yp;
#pragma unroll
        for (int mi = 0; mi < 2; ++mi)
#pragma unroll
            for (int ni = 0; ni < 4; ++ni)
#pragma unroll
                for (int r = 0; r < 4; ++r) {
                    int row = bm + wy * 32 + mi * 16 + g * 4 + r;
                    int col = bn + wx * 64 + ni * 16 + c;
                    Y[(size_t)row * 1024 + col] = acc[mi][ni][r];
                }
    } else {
        ushort* T = smem;                       // [128][136]
#pragma unroll
        for (int mi = 0; mi < 2; ++mi)
#pragma unroll
            for (int ni = 0; ni < 4; ++ni) {
                ushort4 v4;
                v4.x = f2bf(acc[mi][ni][0]); v4.y = f2bf(acc[mi][ni][1]);
                v4.z = f2bf(acc[mi][ni][2]); v4.w = f2bf(acc[mi][ni][3]);
                *(ushort4*)&T[(wx * 64 + ni * 16 + c) * 136 + wy * 32 + mi * 16 + g * 4] = v4;
            }
        __syncthreads();
        ushort* Vt = (ushort*)Yp;
        int b = bm >> 10;
        int rid = tid >> 2, quad = tid & 3;
        int n_c = bn + rid;
        int h = n_c >> 6, d = n_c & 63;
        int m0 = quad * 32;
        ushort* dst = Vt + (size_t)((b * NH_ + h) * 64 + d) * N_ + (bm & (N_ - 1)) + m0;
#pragma unroll
        for (int jj = 0; jj < 4; ++jj)
            *(uint4*)(dst + jj * 8) = *(const uint4*)&T[rid * 136 + m0 + jj * 8];
    }
}

// ---------------------------------------------------------------------------
// Flash-MFMA attention with masked-tile skipping.
// Flat 1D grid: b = id&1, h = (id>>1)&15, t0 = (id>>5)*64 — co-resident WGs
// (stride-256 ids) get t0 spread {a,a+8,a+16,a+24} for load balance.
// Visibility is a prefix (block_ends sorted) => only ceil(cnt[t0+63]/64)
// tiles needed. cnt==0 queries take the Vmean path (reference's finfo.min
// uniform softmax == mean of V).
// ---------------------------------------------------------------------------
__global__ __launch_bounds__(256) void attn_mfma(const ushort* __restrict__ Qp,
                                                 const ushort* __restrict__ Kp,
                                                 const ushort* __restrict__ VtG,
                                                 const int* __restrict__ cnt,
                                                 const float* __restrict__ Vm,
                                                 ushort* __restrict__ AO)
{
    __shared__ __align__(16) ushort Qs[64 * 64];
    __shared__ __align__(16) ushort Ks[64 * 64];
    __shared__ __align__(16) ushort Vs[64 * 64];
    __shared__ __align__(16) ushort Ps[64][72];

    const int id = blockIdx.x;
    const int b = id & 1, h = (id >> 1) & 15, t0 = (id >> 5) << 6;
    const int tid = threadIdx.x, lane = tid & 63, w = tid >> 6;
    const int c = lane & 15, g = lane >> 4;
    const float SC2 = 0.125f * 1.44269504f;   // fold 1/sqrt(D) into exp2 domain

    // stage Q tile (64 q x 64 d), swizzled
#pragma unroll
    for (int j = 0; j < 2; ++j) {
        int u = (w * 2 + j) * 64 + lane;
        int row = u >> 3, gs = (u & 7) ^ (row & 7);
        gload16(Qs + (w * 2 + j) * 512, Qp + (size_t)(b * S_ + t0 + row) * H_ + h * 64 + gs * 8);
    }
    const int cntv = cnt[t0 + w * 16 + c];    // this lane's stats query
    const int cnt_min = cnt[t0];              // min over WG (cnt monotone)
    const int ntmax = (cnt[t0 + 63] + 63) >> 6;

    float m_run = -FLT_MAX, l_run = 0.f;
    f32x4 o[4] = {};

    for (int nt = 0; nt < ntmax; ++nt) {
#pragma unroll
        for (int j = 0; j < 2; ++j) {
            int u = (w * 2 + j) * 64 + lane;
            int row = u >> 3, gs = (u & 7) ^ (row & 7);
            gload16(Ks + (w * 2 + j) * 512, Kp + (size_t)(b * N_ + nt * 64 + row) * H_ + h * 64 + gs * 8);
            gload16(Vs + (w * 2 + j) * 512, VtG + (size_t)((b * NH_ + h) * 64 + row) * N_ + nt * 64 + gs * 8);
        }
        __syncthreads();

        // S^T = K · Q^T
        bf16x8 bq[2];
#pragma unroll
        for (int ks = 0; ks < 2; ++ks) {
            int row = w * 16 + c;
            int s = ks * 4 + g;
            bq[ks] = *(const bf16x8*)(Qs + (row * 8 + (s ^ (row & 7))) * 8);
        }
        f32x4 st[4] = {};
#pragma unroll
        for (int ntile = 0; ntile < 4; ++ntile)
#pragma unroll
            for (int ks = 0; ks < 2; ++ks) {
                int row = ntile * 16 + c;
                int s = ks * 4 + g;
                bf16x8 ak = *(const bf16x8*)(Ks + (row * 8 + (s ^ (row & 7))) * 8);
                st[ntile] = __builtin_amdgcn_mfma_f32_16x16x32_bf16(ak, bq[ks], st[ntile], 0, 0, 0);
            }

        // online softmax in exp2 domain; mask only when tile not fully visible
        const bool full = ((nt + 1) << 6) <= cnt_min;   // wave-uniform
        float sc[4][4];
        float mloc = -FLT_MAX;
#pragma unroll
        for (int ntile = 0; ntile < 4; ++ntile)
#pragma unroll
            for (int r = 0; r < 4; ++r) {
                float v = st[ntile][r] * SC2;
                if (!full) {
                    int n_glob = (nt << 6) + ntile * 16 + g * 4 + r;
                    if (n_glob >= cntv) v = -FLT_MAX;
                }
                sc[ntile][r] = v;
                mloc = fmaxf(mloc, v);
            }
        mloc = fmaxf(mloc, __shfl_xor(mloc, 16));
        mloc = fmaxf(mloc, __shfl_xor(mloc, 32));
        float m_new = fmaxf(m_run, mloc);
        float alpha = fexp2(m_run - m_new);   // -FLT_MAX - -FLT_MAX = 0 -> 1
        float lsum = 0.f;
#pragma unroll
        for (int ntile = 0; ntile < 4; ++ntile) {
            float p0 = fexp2(sc[ntile][0] - m_new);
            float p1 = fexp2(sc[ntile][1] - m_new);
            float p2 = fexp2(sc[ntile][2] - m_new);
            float p3 = fexp2(sc[ntile][3] - m_new);
            lsum += (p0 + p1) + (p2 + p3);
            uint2 pw; pw.x = pk2(p0, p1); pw.y = pk2(p2, p3);
            *(uint2*)&Ps[w * 16 + c][ntile * 16 + g * 4] = pw;   // wave-private rows
        }
        lsum += __shfl_xor(lsum, 16);
        lsum += __shfl_xor(lsum, 32);
        l_run = l_run * alpha + lsum;
        m_run = m_new;

        float ar[4];
#pragma unroll
        for (int r = 0; r < 4; ++r) ar[r] = __shfl(alpha, g * 4 + r);

        bf16x8 ap[2];
#pragma unroll
        for (int ks = 0; ks < 2; ++ks)
            ap[ks] = *(const bf16x8*)&Ps[w * 16 + c][ks * 32 + g * 8];
#pragma unroll
        for (int dt = 0; dt < 4; ++dt) {
            f32x4 oo = o[dt];
#pragma unroll
            for (int r = 0; r < 4; ++r) oo[r] *= ar[r];
#pragma unroll
            for (int ks = 0; ks < 2; ++ks) {
                int row = dt * 16 + c;
                int s = ks * 4 + g;
                bf16x8 bv = *(const bf16x8*)(Vs + (row * 8 + (s ^ (row & 7))) * 8);
                oo = __builtin_amdgcn_mfma_f32_16x16x32_bf16(ap[ks], bv, oo, 0, 0, 0);
            }
            o[dt] = oo;
        }
        __syncthreads();
    }

    float invl = 1.f / l_run;
    float lr[4]; int cq[4];
#pragma unroll
    for (int r = 0; r < 4; ++r) {
        lr[r] = __shfl(invl, g * 4 + r);
        cq[r] = cnt[t0 + w * 16 + g * 4 + r];
    }
#pragma unroll
    for (int dt = 0; dt < 4; ++dt)
#pragma unroll
        for (int r = 0; r < 4; ++r) {
            int q = t0 + w * 16 + g * 4 + r;
            float val = o[dt][r] * lr[r];
            if (cq[r] == 0) val = Vm[((b * NH_ + h) << 6) + dt * 16 + c];
            AO[(size_t)(b * S_ + q) * H_ + h * 64 + dt * 16 + c] = f2bf(val);
        }
}

// ---------------------------------------------------------------------------
extern "C" void kernel_launch(void* const* d_in, const int* in_sizes, int n_in,
                              void* d_out, int out_size, void* d_ws, size_t ws_size,
                              hipStream_t stream) {
    const float* token_q    = (const float*)d_in[0];
    const float* block_kv   = (const float*)d_in[1];
    const int*   block_ends = (const int*)d_in[2];
    const float* Wq = (const float*)d_in[3];
    const float* Wk = (const float*)d_in[4];
    const float* Wv = (const float*)d_in[5];
    const float* Wo = (const float*)d_in[6];
    float* out = (float*)d_out;

    // Workspace (ushort units). qx (bf16 token_q) consumed by Q-proj, then
    // its region is reused as Kp + VtG by the later KV-proj launch. AO
    // aliases Qp (per-WG read-before-write in attn).
    ushort* ws  = (ushort*)d_ws;
    ushort* qx  = ws;                                   // 4M (-> Kp, VtG)
    ushort* Kp  = ws;                                   // 2M
    ushort* VtG = ws + (size_t)2 * 1024 * 1024;         // 2M
    ushort* kvx = ws + (size_t)4 * 1024 * 1024;         // 2M
    ushort* wqb = ws + (size_t)6 * 1024 * 1024;         // 1M
    ushort* wkb = ws + (size_t)7 * 1024 * 1024;         // 1M
    ushort* wvb = ws + (size_t)8 * 1024 * 1024;         // 1M
    ushort* wob = ws + (size_t)9 * 1024 * 1024;         // 1M
    ushort* Qp  = ws + (size_t)10 * 1024 * 1024;        // 4M (AO aliases)
    int*    cnt = (int*)(ws + (size_t)14 * 1024 * 1024);            // 2048 ints
    float*  Vm  = (float*)(ws + (size_t)14 * 1024 * 1024 + 4096);   // 2048 floats

    // fused converts + counts
    prep_kernel<<<5128, 256, 0, stream>>>(token_q, block_kv, Wq, Wk, Wv, Wo,
                                          block_ends, ws, cnt);
    // Q projection
    gemm128<<<dim3(8, 32, 1), 512, 0, stream>>>(qx, wqb, wqb, Qp, Qp, 0);
    // K + V projections (V transposed per head)
    gemm128<<<dim3(8, 16, 2), 512, 0, stream>>>(kvx, wkb, wvb, Kp, VtG, 0);
    // per-(b,h) V mean for fully-masked queries
    vmean_kernel<<<512, 256, 0, stream>>>(VtG, Vm);
    // attention -> AO (aliases Qp)
    attn_mfma<<<1024, 256, 0, stream>>>(Qp, Kp, VtG, cnt, Vm, Qp);
    // output projection -> fp32 out
    gemm128<<<dim3(8, 32, 1), 512, 0, stream>>>(Qp, wob, wob, out, out, 1);
}

// Round 4
// 161.381 us; speedup vs baseline: 5.4515x; 1.1577x over previous
//
#include <hip/hip_runtime.h>
#include <float.h>
#include <stdint.h>

#define B_  2
#define S_  2048
#define N_  1024
#define H_  1024
#define NH_ 16
#define K_  1024

typedef __attribute__((ext_vector_type(8))) short bf16x8;
typedef __attribute__((ext_vector_type(4))) float f32x4;

typedef __attribute__((address_space(3))) uint32_t lds_u32;
typedef __attribute__((address_space(1))) uint32_t glb_u32;

// async global->LDS, 16B per lane; LDS dest = wave-uniform base + lane*16
__device__ __forceinline__ void gload16(void* l, const void* g) {
    __builtin_amdgcn_global_load_lds((const glb_u32*)g, (lds_u32*)l, 16, 0, 0);
}

// round-to-nearest-even fp32 -> bf16 bits
__device__ __forceinline__ ushort f2bf(float f) {
    uint32_t u = __float_as_uint(f);
    u = (u + 0x7fffu + ((u >> 16) & 1u)) >> 16;
    return (ushort)u;
}

#if __has_builtin(__builtin_amdgcn_cvt_pk_bf16_f32)
typedef __attribute__((ext_vector_type(2))) __bf16 bfp2;
__device__ __forceinline__ uint pk2(float a, float b) {
    bfp2 v = __builtin_amdgcn_cvt_pk_bf16_f32(a, b);
    return __builtin_bit_cast(uint, v);
}
#else
__device__ __forceinline__ uint pk2(float a, float b) {
    return (uint)f2bf(a) | ((uint)f2bf(b) << 16);
}
#endif

__device__ __forceinline__ float fexp2(float x) {
#if __has_builtin(__builtin_amdgcn_exp2f)
    return __builtin_amdgcn_exp2f(x);
#else
    return exp2f(x);
#endif
}

#define SC2 0.180336880f   /* (1/sqrt(64)) * log2(e) — folded into Q proj */

// ---------------------------------------------------------------------------
// Fused prep: all fp32->bf16 converts (dst regions contiguous in ws)
// + visibility prefix counts.
// ws layout (ushort units): qx 0..4M | kvx 4M..6M | wq 6M | wk 7M | wv 8M | wo 9M
// ---------------------------------------------------------------------------
__global__ __launch_bounds__(256) void prep_kernel(const float* __restrict__ tq,
        const float* __restrict__ kv, const float* __restrict__ wq,
        const float* __restrict__ wk, const float* __restrict__ wv,
        const float* __restrict__ wo, const int* __restrict__ ends,
        ushort* __restrict__ dst, int* __restrict__ cnt)
{
    int blk = blockIdx.x;
    if (blk >= 5120) {
        int t = (blk - 5120) * 256 + threadIdx.x;
        if (t < S_) {
            int lo = 0, hi = N_;
            while (lo < hi) { int mid = (lo + hi) >> 1; if (ends[mid] <= t) lo = mid + 1; else hi = mid; }
            cnt[t] = lo;
        }
        return;
    }
    const float* src; size_t base;
    if (blk < 2048)      { src = tq; base = 0;       }
    else if (blk < 3072) { src = kv; base = 4194304; blk -= 2048; }
    else if (blk < 3584) { src = wq; base = 6291456; blk -= 3072; }
    else if (blk < 4096) { src = wk; base = 7340032; blk -= 3584; }
    else if (blk < 4608) { src = wv; base = 8388608; blk -= 4096; }
    else                 { src = wo; base = 9437184; blk -= 4608; }
    size_t i = (size_t)blk * 2048 + threadIdx.x * 8;
    float4 a = *(const float4*)(src + i);
    float4 b = *(const float4*)(src + i + 4);
    uint4 o;
    o.x = pk2(a.x, a.y); o.y = pk2(a.z, a.w);
    o.z = pk2(b.x, b.y); o.w = pk2(b.z, b.w);
    *(uint4*)(dst + base + i) = o;
}

// ---------------------------------------------------------------------------
// Vmean[row] = mean over n of Vt[row][n]; row = (b*16+h)*64 + d.
// (= the reference's uniform-softmax output for fully-masked queries.)
// ---------------------------------------------------------------------------
__global__ __launch_bounds__(256) void vmean_kernel(const ushort* __restrict__ Vt,
                                                    float* __restrict__ Vm)
{
    int row = blockIdx.x * 4 + (threadIdx.x >> 6);
    int lane = threadIdx.x & 63;
    const ushort* p = Vt + (size_t)row * N_ + lane * 16;
    uint4 a = *(const uint4*)p;
    uint4 b = *(const uint4*)(p + 8);
    uint u[8] = {a.x, a.y, a.z, a.w, b.x, b.y, b.z, b.w};
    float s = 0.f;
#pragma unroll
    for (int j = 0; j < 8; ++j) {
        s += __uint_as_float(u[j] << 16);
        s += __uint_as_float(u[j] & 0xffff0000u);
    }
#pragma unroll
    for (int off = 1; off < 64; off <<= 1) s += __shfl_xor(s, off);
    if (lane == 0) Vm[row] = s * (1.f / 1024.f);
}

// ---------------------------------------------------------------------------
// Unified 128x128-tile bf16 MFMA GEMM (512 thr = 8 waves, BK=64, XOR-swizzled
// LDS via global_load_lds w=16).
// mode 0 (512 WGs): idx<256 -> Qp = qx@Wq^T * SC2 (bf16); idx<384 -> Kp =
//   kvx@Wk^T (bf16); else -> VtG = transpose-per-head(kvx@Wv^T) (bf16).
// mode 1 (256 WGs): out = AO@Wo^T (fp32).
// ---------------------------------------------------------------------------
__global__ __launch_bounds__(512) void gemm_all(int mode,
        const ushort* __restrict__ qx, const ushort* __restrict__ kvx,
        const ushort* __restrict__ wq, const ushort* __restrict__ wk,
        const ushort* __restrict__ wv, const ushort* __restrict__ wo,
        ushort* __restrict__ Qp, ushort* __restrict__ Kp,
        ushort* __restrict__ VtG, const ushort* __restrict__ AO,
        float* __restrict__ outF)
{
    __shared__ __align__(16) ushort smem[17408];
    ushort* Xs = smem;
    ushort* Ws = smem + 8192;

    const ushort* X; const ushort* W; void* Yp; int kind; float scale = 1.f;
    int bm, bn;
    if (mode == 1) {
        X = AO; W = wo; Yp = outF; kind = 1;
        bm = (blockIdx.x >> 3) * 128; bn = (blockIdx.x & 7) * 128;
    } else {
        int idx = blockIdx.x;
        if (idx < 256)      { X = qx;  W = wq; Yp = Qp;  kind = 0; scale = SC2;
                              bm = (idx >> 3) * 128; bn = (idx & 7) * 128; }
        else if (idx < 384) { int j = idx - 256; X = kvx; W = wk; Yp = Kp; kind = 0;
                              bm = (j >> 3) * 128; bn = (j & 7) * 128; }
        else                { int j = idx - 384; X = kvx; W = wv; Yp = VtG; kind = 2;
                              bm = (j >> 3) * 128; bn = (j & 7) * 128; }
    }

    const int tid = threadIdx.x;
    const int lane = tid & 63, w = tid >> 6;
    const int wy = w >> 1, wx = w & 1;
    const int c = lane & 15, g = lane >> 4;

    f32x4 acc[2][4] = {};

    for (int kt = 0; kt < 16; ++kt) {
        const int k0 = kt * 64;
#pragma unroll
        for (int j = 0; j < 2; ++j) {
            int u = w * 128 + j * 64 + lane;
            int row = u >> 3, gs = (u & 7) ^ (row & 7);
            gload16(Xs + (w * 128 + j * 64) * 8, X + (size_t)(bm + row) * K_ + k0 + gs * 8);
            gload16(Ws + (w * 128 + j * 64) * 8, W + (size_t)(bn + row) * K_ + k0 + gs * 8);
        }
        __syncthreads();
#pragma unroll
        for (int ks = 0; ks < 2; ++ks) {
            bf16x8 af[2], bfr[4];
#pragma unroll
            for (int mi = 0; mi < 2; ++mi) {
                int row = wy * 32 + mi * 16 + c;
                int s = ks * 4 + g;
                af[mi] = *(const bf16x8*)(Xs + (row * 8 + (s ^ (row & 7))) * 8);
            }
#pragma unroll
            for (int ni = 0; ni < 4; ++ni) {
                int row = wx * 64 + ni * 16 + c;
                int s = ks * 4 + g;
                bfr[ni] = *(const bf16x8*)(Ws + (row * 8 + (s ^ (row & 7))) * 8);
            }
#pragma unroll
            for (int mi = 0; mi < 2; ++mi)
#pragma unroll
                for (int ni = 0; ni < 4; ++ni)
                    acc[mi][ni] = __builtin_amdgcn_mfma_f32_16x16x32_bf16(af[mi], bfr[ni], acc[mi][ni], 0, 0, 0);
        }
        __syncthreads();
    }

    if (kind == 0) {
        ushort* Y = (ushort*)Yp;
#pragma unroll
        for (int mi = 0; mi < 2; ++mi)
#pragma unroll
            for (int ni = 0; ni < 4; ++ni)
#pragma unroll
                for (int r = 0; r < 4; ++r) {
                    int row = bm + wy * 32 + mi * 16 + g * 4 + r;
                    int col = bn + wx * 64 + ni * 16 + c;
                    Y[(size_t)row * 1024 + col] = f2bf(acc[mi][ni][r] * scale);
                }
    } else if (kind == 1) {
        float* Y = (float*)Yp;
#pragma unroll
        for (int mi = 0; mi < 2; ++mi)
#pragma unroll
            for (int ni = 0; ni < 4; ++ni)
#pragma unroll
                for (int r = 0; r < 4; ++r) {
                    int row = bm + wy * 32 + mi * 16 + g * 4 + r;
                    int col = bn + wx * 64 + ni * 16 + c;
                    Y[(size_t)row * 1024 + col] = acc[mi][ni][r];
                }
    } else {
        ushort* T = smem;                       // [128][136]
#pragma unroll
        for (int mi = 0; mi < 2; ++mi)
#pragma unroll
            for (int ni = 0; ni < 4; ++ni) {
                ushort4 v4;
                v4.x = f2bf(acc[mi][ni][0]); v4.y = f2bf(acc[mi][ni][1]);
                v4.z = f2bf(acc[mi][ni][2]); v4.w = f2bf(acc[mi][ni][3]);
                *(ushort4*)&T[(wx * 64 + ni * 16 + c) * 136 + wy * 32 + mi * 16 + g * 4] = v4;
            }
        __syncthreads();
        ushort* Vt = (ushort*)Yp;
        int b = bm >> 10;
        int rid = tid >> 2, quad = tid & 3;
        int n_c = bn + rid;
        int h = n_c >> 6, d = n_c & 63;
        int m0 = quad * 32;
        ushort* dst = Vt + (size_t)((b * NH_ + h) * 64 + d) * N_ + (bm & (N_ - 1)) + m0;
#pragma unroll
        for (int jj = 0; jj < 4; ++jj)
            *(uint4*)(dst + jj * 8) = *(const uint4*)&T[rid * 136 + m0 + jj * 8];
    }
}

// ---------------------------------------------------------------------------
// Flash-MFMA attention, no-max softmax (scores bounded; Q pre-scaled by
// SC2 so exp2 input is the raw MFMA output). Masked entries contribute p=0.
// Fully-masked queries (cnt==0) take the Vmean path (= reference's finfo.min
// uniform softmax). Prefix visibility => only ceil(cnt[t0+63]/64) tiles.
// ---------------------------------------------------------------------------
__global__ __launch_bounds__(256) void attn_mfma(const ushort* __restrict__ Qp,
                                                 const ushort* __restrict__ Kp,
                                                 const ushort* __restrict__ VtG,
                                                 const int* __restrict__ cnt,
                                                 const float* __restrict__ Vm,
                                                 ushort* __restrict__ AO)
{
    __shared__ __align__(16) ushort Qs[64 * 64];
    __shared__ __align__(16) ushort Ks[64 * 64];
    __shared__ __align__(16) ushort Vs[64 * 64];
    __shared__ __align__(16) ushort Ps[64][72];

    const int id = blockIdx.x;
    const int b = id & 1, h = (id >> 1) & 15, t0 = (id >> 5) << 6;
    const int tid = threadIdx.x, lane = tid & 63, w = tid >> 6;
    const int c = lane & 15, g = lane >> 4;

    // stage Q tile (64 q x 64 d), swizzled
    {
        int u0 = (w * 2) * 64 + lane;
        int row0 = u0 >> 3, gs0 = (u0 & 7) ^ (row0 & 7);
        gload16(Qs + (w * 2) * 512, Qp + (size_t)(b * S_ + t0 + row0) * H_ + h * 64 + gs0 * 8);
        int u1 = (w * 2 + 1) * 64 + lane;
        int row1 = u1 >> 3, gs1 = (u1 & 7) ^ (row1 & 7);
        gload16(Qs + (w * 2 + 1) * 512, Qp + (size_t)(b * S_ + t0 + row1) * H_ + h * 64 + gs1 * 8);
    }
    const int cntv = cnt[t0 + w * 16 + c];
    const int cnt_min = cnt[t0];
    const int ntmax = (cnt[t0 + 63] + 63) >> 6;

    // staging addresses (loop-invariant parts)
    const int u0 = (w * 2) * 64 + lane, row0 = u0 >> 3, gs0 = (u0 & 7) ^ (row0 & 7);
    const int u1 = (w * 2 + 1) * 64 + lane, row1 = u1 >> 3, gs1 = (u1 & 7) ^ (row1 & 7);
    const ushort* kp0 = Kp + (size_t)(b * N_ + row0) * H_ + h * 64 + gs0 * 8;
    const ushort* kp1 = Kp + (size_t)(b * N_ + row1) * H_ + h * 64 + gs1 * 8;
    const ushort* vp0 = VtG + (size_t)((b * NH_ + h) * 64 + row0) * N_ + gs0 * 8;
    const ushort* vp1 = VtG + (size_t)((b * NH_ + h) * 64 + row1) * N_ + gs1 * 8;

    float l_run = 0.f;
    f32x4 o[4] = {};

    __syncthreads();
    // Q fragments: loop-invariant, hoisted
    bf16x8 bq[2];
#pragma unroll
    for (int ks = 0; ks < 2; ++ks) {
        int row = w * 16 + c;
        int s = ks * 4 + g;
        bq[ks] = *(const bf16x8*)(Qs + (row * 8 + (s ^ (row & 7))) * 8);
    }

    for (int nt = 0; nt < ntmax; ++nt) {
        gload16(Ks + (w * 2) * 512, kp0 + (size_t)nt * 64 * H_);
        gload16(Ks + (w * 2 + 1) * 512, kp1 + (size_t)nt * 64 * H_);
        gload16(Vs + (w * 2) * 512, vp0 + nt * 64);
        gload16(Vs + (w * 2 + 1) * 512, vp1 + nt * 64);
        __syncthreads();

        // S^T = K · Q^T  (Q pre-scaled by SC2)
        f32x4 st[4] = {};
#pragma unroll
        for (int ntile = 0; ntile < 4; ++ntile)
#pragma unroll
            for (int ks = 0; ks < 2; ++ks) {
                int row = ntile * 16 + c;
                int s = ks * 4 + g;
                bf16x8 ak = *(const bf16x8*)(Ks + (row * 8 + (s ^ (row & 7))) * 8);
                st[ntile] = __builtin_amdgcn_mfma_f32_16x16x32_bf16(ak, bq[ks], st[ntile], 0, 0, 0);
            }

        // no-max softmax: p = exp2(st) (0 if masked); accumulate l
        const bool full = ((nt + 1) << 6) <= cnt_min;   // wave-uniform
        float lsum = 0.f;
        if (full) {
#pragma unroll
            for (int ntile = 0; ntile < 4; ++ntile) {
                float p0 = fexp2(st[ntile][0]);
                float p1 = fexp2(st[ntile][1]);
                float p2 = fexp2(st[ntile][2]);
                float p3 = fexp2(st[ntile][3]);
                lsum += (p0 + p1) + (p2 + p3);
                uint2 pw; pw.x = pk2(p0, p1); pw.y = pk2(p2, p3);
                *(uint2*)&Ps[w * 16 + c][ntile * 16 + g * 4] = pw;
            }
        } else {
            const int base = (nt << 6) + g * 4 - cntv;  // masked iff ntile*16+r+base >= 0
#pragma unroll
            for (int ntile = 0; ntile < 4; ++ntile) {
                float p0 = (base + ntile * 16 + 0 >= 0) ? 0.f : fexp2(st[ntile][0]);
                float p1 = (base + ntile * 16 + 1 >= 0) ? 0.f : fexp2(st[ntile][1]);
                float p2 = (base + ntile * 16 + 2 >= 0) ? 0.f : fexp2(st[ntile][2]);
                float p3 = (base + ntile * 16 + 3 >= 0) ? 0.f : fexp2(st[ntile][3]);
                lsum += (p0 + p1) + (p2 + p3);
                uint2 pw; pw.x = pk2(p0, p1); pw.y = pk2(p2, p3);
                *(uint2*)&Ps[w * 16 + c][ntile * 16 + g * 4] = pw;
            }
        }
        lsum += __shfl_xor(lsum, 16);
        lsum += __shfl_xor(lsum, 32);
        l_run += lsum;

        // O += P · V   (A = Ps rows [wave-private], B = Vt rows)
        bf16x8 ap[2];
#pragma unroll
        for (int ks = 0; ks < 2; ++ks)
            ap[ks] = *(const bf16x8*)&Ps[w * 16 + c][ks * 32 + g * 8];
#pragma unroll
        for (int dt = 0; dt < 4; ++dt) {
#pragma unroll
            for (int ks = 0; ks < 2; ++ks) {
                int row = dt * 16 + c;
                int s = ks * 4 + g;
                bf16x8 bv = *(const bf16x8*)(Vs + (row * 8 + (s ^ (row & 7))) * 8);
                o[dt] = __builtin_amdgcn_mfma_f32_16x16x32_bf16(ap[ks], bv, o[dt], 0, 0, 0);
            }
        }
        __syncthreads();
    }

    float invl = 1.f / l_run;
    float lr[4]; int cq[4];
#pragma unroll
    for (int r = 0; r < 4; ++r) {
        lr[r] = __shfl(invl, g * 4 + r);
        cq[r] = cnt[t0 + w * 16 + g * 4 + r];
    }
#pragma unroll
    for (int dt = 0; dt < 4; ++dt)
#pragma unroll
        for (int r = 0; r < 4; ++r) {
            int q = t0 + w * 16 + g * 4 + r;
            float val = o[dt][r] * lr[r];
            if (cq[r] == 0) val = Vm[((b * NH_ + h) << 6) + dt * 16 + c];
            AO[(size_t)(b * S_ + q) * H_ + h * 64 + dt * 16 + c] = f2bf(val);
        }
}

// ---------------------------------------------------------------------------
extern "C" void kernel_launch(void* const* d_in, const int* in_sizes, int n_in,
                              void* d_out, int out_size, void* d_ws, size_t ws_size,
                              hipStream_t stream) {
    const float* token_q    = (const float*)d_in[0];
    const float* block_kv   = (const float*)d_in[1];
    const int*   block_ends = (const int*)d_in[2];
    const float* Wq = (const float*)d_in[3];
    const float* Wk = (const float*)d_in[4];
    const float* Wv = (const float*)d_in[5];
    const float* Wo = (const float*)d_in[6];
    float* out = (float*)d_out;

    // ws layout (ushort units) — no aliasing between concurrent QKV WGs:
    // qx 0..4M | kvx 4..6M | wq 6M | wk 7M | wv 8M | wo 9M | Qp 10..14M (AO
    // aliases Qp: per-WG read-before-write) | Kp 14..16M | VtG 16..18M | cnt/Vm
    ushort* ws  = (ushort*)d_ws;
    ushort* qx  = ws;
    ushort* kvx = ws + (size_t)4 * 1024 * 1024;
    ushort* wqb = ws + (size_t)6 * 1024 * 1024;
    ushort* wkb = ws + (size_t)7 * 1024 * 1024;
    ushort* wvb = ws + (size_t)8 * 1024 * 1024;
    ushort* wob = ws + (size_t)9 * 1024 * 1024;
    ushort* Qp  = ws + (size_t)10 * 1024 * 1024;
    ushort* Kp  = ws + (size_t)14 * 1024 * 1024;
    ushort* VtG = ws + (size_t)16 * 1024 * 1024;
    int*    cnt = (int*)(ws + (size_t)18 * 1024 * 1024);
    float*  Vm  = (float*)(ws + (size_t)18 * 1024 * 1024 + 4096);

    // fused converts + counts
    prep_kernel<<<5128, 256, 0, stream>>>(token_q, block_kv, Wq, Wk, Wv, Wo,
                                          block_ends, ws, cnt);
    // fused Q + K + V projections (512 WGs = 2/CU)
    gemm_all<<<512, 512, 0, stream>>>(0, qx, kvx, wqb, wkb, wvb, wob,
                                      Qp, Kp, VtG, nullptr, nullptr);
    // per-(b,h) V mean for fully-masked queries
    vmean_kernel<<<512, 256, 0, stream>>>(VtG, Vm);
    // attention -> AO (aliases Qp)
    attn_mfma<<<1024, 256, 0, stream>>>(Qp, Kp, VtG, cnt, Vm, Qp);
    // output projection -> fp32 out
    gemm_all<<<256, 512, 0, stream>>>(1, qx, kvx, wqb, wkb, wvb, wob,
                                      Qp, Kp, VtG, Qp, out);
}